// Round 4
// baseline (81033.325 us; speedup 1.0000x reference)
//
#include <hip/hip_runtime.h>

#define TT 8192
#define DD 2048
#define NWG 128
#define NTH 256
#define NREP 16         // replica h-buffers; lane = rep*4+row stores one dword

typedef unsigned long long u64;
typedef unsigned int u32;
#define SIGN2 0x8000000080000000ULL
#define SIGN1 0x80000000u

// ---------------- Phase 1: pre = x @ W1^T + b1  (M=TT, N=DD, K=DD) ----------
#define BM 128
#define BN 128
#define BK 16

__global__ __launch_bounds__(NTH)
void gemm_abt_bias(const float* __restrict__ A, const float* __restrict__ B,
                   const float* __restrict__ bias, float* __restrict__ C,
                   int M, int N, int K) {
  __shared__ float As[BK][BM + 4];
  __shared__ float Bs[BK][BN + 4];
  const int ntile = N / BN;
  const int bn = blockIdx.x % ntile;
  const int bm = blockIdx.x / ntile;
  const int tid = (int)threadIdx.x;
  const int tx = tid & 15;
  const int ty = tid >> 4;

  float acc[8][8];
#pragma unroll
  for (int i = 0; i < 8; ++i)
#pragma unroll
    for (int j = 0; j < 8; ++j) acc[i][j] = 0.f;

  for (int kt = 0; kt < K; kt += BK) {
#pragma unroll
    for (int i = 0; i < 2; ++i) {
      int f = tid + i * 256;
      int row = f >> 2, c4 = f & 3;
      const float4 av = *(const float4*)(A + (size_t)(bm * BM + row) * K + kt + c4 * 4);
      As[c4 * 4 + 0][row] = av.x; As[c4 * 4 + 1][row] = av.y;
      As[c4 * 4 + 2][row] = av.z; As[c4 * 4 + 3][row] = av.w;
      const float4 bv = *(const float4*)(B + (size_t)(bn * BN + row) * K + kt + c4 * 4);
      Bs[c4 * 4 + 0][row] = bv.x; Bs[c4 * 4 + 1][row] = bv.y;
      Bs[c4 * 4 + 2][row] = bv.z; Bs[c4 * 4 + 3][row] = bv.w;
    }
    __syncthreads();
#pragma unroll
    for (int kk = 0; kk < BK; ++kk) {
      float a[8], b[8];
      *(float4*)&a[0] = *(const float4*)&As[kk][ty * 8];
      *(float4*)&a[4] = *(const float4*)&As[kk][ty * 8 + 4];
      *(float4*)&b[0] = *(const float4*)&Bs[kk][tx * 8];
      *(float4*)&b[4] = *(const float4*)&Bs[kk][tx * 8 + 4];
#pragma unroll
      for (int i = 0; i < 8; ++i)
#pragma unroll
        for (int j = 0; j < 8; ++j) acc[i][j] += a[i] * b[j];
    }
    __syncthreads();
  }

  const int col0 = bn * BN + tx * 8;
  const float4 bv0 = *(const float4*)(bias + col0);
  const float4 bv1 = *(const float4*)(bias + col0 + 4);
#pragma unroll
  for (int i = 0; i < 8; ++i) {
    float* crow = C + (size_t)(bm * BM + ty * 8 + i) * N + col0;
    float4 v0 = { acc[i][0] + bv0.x, acc[i][1] + bv0.y, acc[i][2] + bv0.z, acc[i][3] + bv0.w };
    float4 v1 = { acc[i][4] + bv1.x, acc[i][5] + bv1.y, acc[i][6] + bv1.z, acc[i][7] + bv1.w };
    *(float4*)(crow) = v0;
    *(float4*)(crow + 4) = v1;
  }
}

// ---------------- Phase 2: persistent recurrent kernel ----------------------
__device__ __forceinline__ float wave_sum(float v) {
#pragma unroll
  for (int off = 32; off > 0; off >>= 1) v += __shfl_down(v, off, 64);
  return v;
}

__device__ __forceinline__ u64 aload(const u64* p) {
  return __hip_atomic_load(p, __ATOMIC_RELAXED, __HIP_MEMORY_SCOPE_AGENT);
}
__device__ __forceinline__ void astore32(u32* p, u32 v) {
  __hip_atomic_store(p, v, __ATOMIC_RELAXED, __HIP_MEMORY_SCOPE_AGENT);
}

// Round-4 protocol: wave-autonomous steps, ZERO barriers in the t-loop.
// All proven invariants kept: relaxed agent-scope only (round-1 lesson:
// anything below agent scope serves period-4 tag-valid stale data); per-DWORD
// parity tags in sign bits of ReLU-nonnegative h; slot = t&1, tag = (t>>1)&1;
// anti-poison slot0=0x00 / slot1=0xAA.
//  * Each of 512 waves (wid = wg*4+wave) owns 4 complete output rows
//    R=wid*4..R+3 over ALL k. Lane owns k in [32*lane, 32*lane+32) -> 4x32
//    = 128 FMA/lane, W2 slice = 128 VGPRs (rows permuted: slot j = row j^p2,
//    p2 = bitrev2(lane&3), so the 7-shuffle fold aligns give/keep halves).
//  * Consumer: lane polls its 16 u64s (128 B) of replica grp = wid&15.
//    Per 64B line: 32 waves/replica x 1 lane = 32 pollers (the round-2-
//    winning contention level; NREP doubled to compensate 4x poll breadth).
//  * Fold (in-wave, wave-synchronous, no sync needed): stages xor 1,2 fold
//    rows (partner slot aligns since lane bit0<->p2 bit1, bit1<->bit0),
//    stages 4..32 accumulate. Lane ends with full sum of row R+p2.
//  * Store: broadcast row j=lane&3 from lane p2 (involution), add pre+b2,
//    ReLU, tag, one dword store to replica rep=lane>>2 (64 lanes = 16 reps
//    x 4 rows exactly; dword-granular stores are safe: tags are per dword).
//  * ABA induction unchanged: a wave stores h_{t+2} only after detecting ALL
//    of h_{t+1}; any h_{t+1} chunk from wave U implies U consumed all of h_t
//    from registers that passed the tag check. So no h_{t+2} store can land
//    before every reader of h_t (same addresses) is done.
__global__ void __launch_bounds__(NTH, 1)
recurrent_kernel(const float* __restrict__ h0,
                 const float* __restrict__ W2,
                 const float* __restrict__ b2,
                 const float* __restrict__ pre,
                 const float* __restrict__ Wf,
                 const float* __restrict__ bf,
                 float* __restrict__ out,
                 float* hbuf) {     // 2 * NREP * DD floats
  __shared__ float hs[DD];          // epilogue only

  const int wg   = (int)blockIdx.x;
  const int tid  = (int)threadIdx.x;
  const int lane = tid & 63;
  const int wave = tid >> 6;
  const int wid  = wg * 4 + wave;          // global wave id, 0..511
  const int grp  = wid & (NREP - 1);
  const int R    = wid * 4;                // my 4 rows: R..R+3
  const int p2   = ((lane & 1) << 1) | ((lane & 2) >> 1);  // bitrev2(lane&3)
  const int k0   = lane * 32;              // my k-slice

  // W2: 4 permuted rows x my 32 k = 128 VGPRs, pinned.
  float w2[128];
#pragma unroll
  for (int j = 0; j < 4; ++j) {
    const size_t r = (size_t)(R + (j ^ p2));
#pragma unroll
    for (int q = 0; q < 8; ++q)
      *(float4*)&w2[j * 32 + q * 4] = *(const float4*)(W2 + r * DD + k0 + q * 4);
  }
#pragma unroll
  for (int i = 0; i < 128; i += 4)
    asm volatile("" : "+v"(w2[i]), "+v"(w2[i+1]), "+v"(w2[i+2]), "+v"(w2[i+3]));

  const int myrow = R + (lane & 3);        // row this lane combines/stores
  const float b2v = b2[myrow];
  const int rep   = lane >> 2;             // replica this lane stores to

  u64* const hbU = (u64*)hbuf;   // u64 index: ((slot*NREP)+rep)*(DD/2) + i

  for (int t = 0; t < TT; ++t) {
    const float prev = pre[(size_t)t * DD + myrow];   // prefetch pre-poll

    float h[32];
    if (t == 0) {
#pragma unroll
      for (int q = 0; q < 8; ++q) {
        const float4 a = *(const float4*)(h0 + k0 + q * 4);
        h[q*4+0]=a.x; h[q*4+1]=a.y; h[q*4+2]=a.z; h[q*4+3]=a.w;
      }
    } else {
      u64* src = hbU + (size_t)((t & 1) * NREP + grp) * (DD / 2) + lane * 16;
      u64 u[16];
      if (((t >> 1) & 1) == 0) {        // expect all sign bits CLEAR
        for (;;) {
          u64 m = 0ULL;
#pragma unroll
          for (int i = 0; i < 16; ++i) { u[i] = aload(src + i); m |= u[i]; }
          if ((m & SIGN2) == 0ULL) break;
          __builtin_amdgcn_s_sleep(1);
        }
      } else {                          // expect all sign bits SET
        for (;;) {
          u64 m = ~0ULL;
#pragma unroll
          for (int i = 0; i < 16; ++i) { u[i] = aload(src + i); m &= u[i]; }
          if ((~m & SIGN2) == 0ULL) break;
          __builtin_amdgcn_s_sleep(1);
        }
      }
#pragma unroll
      for (int i = 0; i < 16; ++i) {
        h[2*i]   = __uint_as_float((u32)u[i] & 0x7fffffffu);
        h[2*i+1] = __uint_as_float((u32)(u[i] >> 32) & 0x7fffffffu);
      }
    }

    // 4 permuted rows x 32 k straight from registers.
    float acc[4] = {0.f, 0.f, 0.f, 0.f};
#pragma unroll
    for (int i = 0; i < 32; ++i)
#pragma unroll
      for (int j = 0; j < 4; ++j) acc[j] += w2[j * 32 + i] * h[i];

    // 7-shuffle fold; lane ends with full 64-lane sum of row R + p2.
    acc[0] += __shfl_xor(acc[2], 1, 64);
    acc[1] += __shfl_xor(acc[3], 1, 64);
    acc[0] += __shfl_xor(acc[1], 2, 64);
    acc[0] += __shfl_xor(acc[0], 4, 64);
    acc[0] += __shfl_xor(acc[0], 8, 64);
    acc[0] += __shfl_xor(acc[0], 16, 64);
    acc[0] += __shfl_xor(acc[0], 32, 64);

    // Broadcast row (lane&3) from lane p2 (p2 is an involution on 0..3).
    float v = __shfl(acc[0], p2, 64);
    v = fmaxf(v + prev + b2v, 0.f);
    u32 b = __float_as_uint(v);               // sign bit 0 (v >= 0)
    if (((t + 1) >> 1) & 1) b |= SIGN1;
    u32* dst = (u32*)hbuf + (size_t)(((t + 1) & 1) * NREP + rep) * DD + myrow;
    astore32(dst, b);
  }

  if (wg != 0) return;

  // WG0 epilogue: out = Wf @ h_TT + bf. h_8192: slot 0, rep 0, tag 0.
  {
    u64* src = hbU + 4 * tid;
    u64 u0, u1, u2, u3;
    for (;;) {
      u0 = aload(src + 0); u1 = aload(src + 1);
      u2 = aload(src + 2); u3 = aload(src + 3);
      if ((((u0 | u1) | (u2 | u3)) & SIGN2) == 0ULL) break;
      __builtin_amdgcn_s_sleep(1);
    }
    u64* dst = (u64*)hs + 4 * tid;
    dst[0] = u0; dst[1] = u1; dst[2] = u2; dst[3] = u3;
  }
  __syncthreads();
  float acc = 0.f;
#pragma unroll
  for (int j = 0; j < 8; ++j) {
    const float4 wv = *(const float4*)(Wf + (size_t)wave * DD + j * 256 + 4 * lane);
    const float4 hv = *(const float4*)&hs[j * 256 + 4 * lane];
    acc += wv.x * hv.x + wv.y * hv.y + wv.z * hv.z + wv.w * hv.w;
  }
  acc = wave_sum(acc);
  if (lane == 0) out[wave] = acc + bf[wave];
}

// ---------------- Launch ----------------------------------------------------
extern "C" void kernel_launch(void* const* d_in, const int* in_sizes, int n_in,
                              void* d_out, int out_size, void* d_ws, size_t ws_size,
                              hipStream_t stream) {
  const float* x  = (const float*)d_in[0];
  const float* h0 = (const float*)d_in[1];
  const float* W1 = (const float*)d_in[2];
  const float* b1 = (const float*)d_in[3];
  const float* W2 = (const float*)d_in[4];
  const float* b2 = (const float*)d_in[5];
  const float* Wf = (const float*)d_in[6];
  const float* bf = (const float*)d_in[7];
  float* out = (float*)d_out;

  // Workspace: pre (64 MB) | hbuf (2 slots x NREP x DD floats = 256 KB)
  float* pre  = (float*)d_ws;
  float* hbuf = pre + (size_t)TT * DD;

  // Anti-poison slot init (see kernel comment).
  hipMemsetAsync(hbuf, 0x00, NREP * DD * sizeof(float), stream);              // slot0
  hipMemsetAsync(hbuf + NREP * DD, 0xAA, NREP * DD * sizeof(float), stream);  // slot1

  gemm_abt_bias<<<dim3((TT / BM) * (DD / BN)), dim3(NTH), 0, stream>>>(
      x, W1, b1, pre, TT, DD, DD);
  recurrent_kernel<<<dim3(NWG), dim3(NTH), 0, stream>>>(
      h0, W2, b2, pre, Wf, bf, out, hbuf);
}

// Round 6
// 18323.108 us; speedup vs baseline: 4.4225x; 4.4225x over previous
//
#include <hip/hip_runtime.h>

#define TT 8192
#define DD 2048
#define NWG 128
#define RPW 16          // rows of h per workgroup (DD / NWG)
#define NTH 256
#define NREP 8          // replica h-buffers to spread LLC poll hotspot

typedef unsigned long long u64;
typedef unsigned int u32;
#define SIGN2 0x8000000080000000ULL
#define SIGN1 0x80000000u

// ---------------- Phase 1: pre = x @ W1^T + b1  (M=TT, N=DD, K=DD) ----------
#define BM 128
#define BN 128
#define BK 16

__global__ __launch_bounds__(NTH)
void gemm_abt_bias(const float* __restrict__ A, const float* __restrict__ B,
                   const float* __restrict__ bias, float* __restrict__ C,
                   int M, int N, int K) {
  __shared__ float As[BK][BM + 4];
  __shared__ float Bs[BK][BN + 4];
  const int ntile = N / BN;
  const int bn = blockIdx.x % ntile;
  const int bm = blockIdx.x / ntile;
  const int tid = (int)threadIdx.x;
  const int tx = tid & 15;
  const int ty = tid >> 4;

  float acc[8][8];
#pragma unroll
  for (int i = 0; i < 8; ++i)
#pragma unroll
    for (int j = 0; j < 8; ++j) acc[i][j] = 0.f;

  for (int kt = 0; kt < K; kt += BK) {
#pragma unroll
    for (int i = 0; i < 2; ++i) {
      int f = tid + i * 256;
      int row = f >> 2, c4 = f & 3;
      const float4 av = *(const float4*)(A + (size_t)(bm * BM + row) * K + kt + c4 * 4);
      As[c4 * 4 + 0][row] = av.x; As[c4 * 4 + 1][row] = av.y;
      As[c4 * 4 + 2][row] = av.z; As[c4 * 4 + 3][row] = av.w;
      const float4 bv = *(const float4*)(B + (size_t)(bn * BN + row) * K + kt + c4 * 4);
      Bs[c4 * 4 + 0][row] = bv.x; Bs[c4 * 4 + 1][row] = bv.y;
      Bs[c4 * 4 + 2][row] = bv.z; Bs[c4 * 4 + 3][row] = bv.w;
    }
    __syncthreads();
#pragma unroll
    for (int kk = 0; kk < BK; ++kk) {
      float a[8], b[8];
      *(float4*)&a[0] = *(const float4*)&As[kk][ty * 8];
      *(float4*)&a[4] = *(const float4*)&As[kk][ty * 8 + 4];
      *(float4*)&b[0] = *(const float4*)&Bs[kk][tx * 8];
      *(float4*)&b[4] = *(const float4*)&Bs[kk][tx * 8 + 4];
#pragma unroll
      for (int i = 0; i < 8; ++i)
#pragma unroll
        for (int j = 0; j < 8; ++j) acc[i][j] += a[i] * b[j];
    }
    __syncthreads();
  }

  const int col0 = bn * BN + tx * 8;
  const float4 bv0 = *(const float4*)(bias + col0);
  const float4 bv1 = *(const float4*)(bias + col0 + 4);
#pragma unroll
  for (int i = 0; i < 8; ++i) {
    float* crow = C + (size_t)(bm * BM + ty * 8 + i) * N + col0;
    float4 v0 = { acc[i][0] + bv0.x, acc[i][1] + bv0.y, acc[i][2] + bv0.z, acc[i][3] + bv0.w };
    float4 v1 = { acc[i][4] + bv1.x, acc[i][5] + bv1.y, acc[i][6] + bv1.z, acc[i][7] + bv1.w };
    *(float4*)(crow) = v0;
    *(float4*)(crow + 4) = v1;
  }
}

// ---------------- Phase 2: persistent recurrent kernel ----------------------
__device__ __forceinline__ float wave_sum(float v) {
#pragma unroll
  for (int off = 32; off > 0; off >>= 1) v += __shfl_down(v, off, 64);
  return v;
}

__device__ __forceinline__ u64 aload(const u64* p) {
  return __hip_atomic_load(p, __ATOMIC_RELAXED, __HIP_MEMORY_SCOPE_AGENT);
}
__device__ __forceinline__ void astore32(u32* p, u32 v) {
  __hip_atomic_store(p, v, __ATOMIC_RELAXED, __HIP_MEMORY_SCOPE_AGENT);
}

// Round-5 protocol = round-3 protocol (proven: relaxed agent-scope only;
// per-dword parity tags in sign bits; slot = t&1, tag = (t>>1)&1; NREP=8
// replicas; consumer thread polls u64s 4*tid..4*tid+3 of replica wg&7;
// anti-poison slot0=0x00/slot1=0xAA) with ONE structural change:
//
//  * NO barrier in the t-loop. Each wave: fold -> ds_write partial[par] ->
//    lgkmcnt(0) -> lane0 atomicAdd(cnt[par]). The LAST wave (old==3) combines
//    with all 64 lanes (row = lane&15, p = lane>>4: 1 ds_read + shfl_xor 16,32
//    -> full row sums replicated x4), resets cnt[par], then stores the WG's
//    full 64B h-line per replica: lanes with rep=lane>>4 store 1 dword each
//    (16 consecutive dwords per 16-lane group = coalesced FULL-LINE store
//    from ONE wave — round-4 lesson: scattered sub-line stores from multiple
//    waves cause LLC churn + HBM thrash; full-line single-wave stores don't).
//    Each lane stores reps (lane>>4) and (lane>>4)+4 -> all 8 replicas.
//    Per-dword tags make dword-granular stores sound (consumer u64 checks
//    both halves' sign bits).
//  * Non-combiner waves fall straight into the next step's poll -> their
//    detect loads are in flight while the combiner finishes (overlap).
//  * Reuse safety (induction, as before): any write to partial[par]/cnt[par]
//    at t+2 requires detecting h_{t+2} <= every WG's t+1 combine <= all waves
//    detected h_{t+1} incl. our rows <= our t-combiner stored h_{t+1} <=
//    (program order + lgkmcnt(0)) it already read partial[par] and reset
//    cnt[par]. ABA on h-slots unchanged from round 3.
__global__ void __launch_bounds__(NTH, 1)
recurrent_kernel(const float* __restrict__ h0,
                 const float* __restrict__ W2,
                 const float* __restrict__ b2,
                 const float* __restrict__ pre,
                 const float* __restrict__ Wf,
                 const float* __restrict__ bf,
                 float* __restrict__ out,
                 float* hbuf) {     // 2 * NREP * DD floats
  __shared__ float partial[2][4][RPW];   // [t&1][wave][row]
  __shared__ int   scnt[2];              // arrival counters, parity-indexed
  __shared__ float hs[DD];               // epilogue only

  const int wg   = (int)blockIdx.x;
  const int tid  = (int)threadIdx.x;
  const int lane = tid & 63;
  const int wave = tid >> 6;
  const int grp  = wg & (NREP - 1);
  const int k0   = 8 * tid;            // this thread's k-slice

  // bitrev4 of low lane bits: lane bit0->lp bit3, b1->b2, b2->b1, b3->b0.
  const int lp = ((lane & 1) << 3) | ((lane & 2) << 1) |
                 ((lane & 4) >> 1) | ((lane & 8) >> 3);

  // W2 for all 16 WG rows x my 8 k values, rows permuted per-lane for the
  // fold (slot j = row j ^ lp). 128 VGPRs, pinned.
  float w2[RPW * 8];
#pragma unroll
  for (int j = 0; j < RPW; ++j) {
    const size_t r = (size_t)(wg * RPW + (j ^ lp));
    *(float4*)&w2[j * 8]     = *(const float4*)(W2 + r * DD + k0);
    *(float4*)&w2[j * 8 + 4] = *(const float4*)(W2 + r * DD + k0 + 4);
  }
#pragma unroll
  for (int i = 0; i < RPW * 8; i += 4)
    asm volatile("" : "+v"(w2[i]), "+v"(w2[i + 1]), "+v"(w2[i + 2]), "+v"(w2[i + 3]));

  // Combine constants: every lane (any wave may combine): row = lane&15.
  const int crow = wg * RPW + (lane & 15);
  const float b2v = b2[crow];

  if (tid == 0) { scnt[0] = 0; scnt[1] = 0; }
  __syncthreads();   // one-time init barrier (outside the t-loop)

  u64* const hbU = (u64*)hbuf;   // u64 index: ((slot*NREP)+rep)*(DD/2) + i

  for (int t = 0; t < TT; ++t) {
    const int par = t & 1;
    // Prefetch pre for the (possible) combine, issued pre-poll.
    const float preh = pre[(size_t)t * DD + crow];

    float h[8];
    if (t == 0) {
      const float4 a = *(const float4*)(h0 + k0);
      const float4 b = *(const float4*)(h0 + k0 + 4);
      h[0]=a.x; h[1]=a.y; h[2]=a.z; h[3]=a.w;
      h[4]=b.x; h[5]=b.y; h[6]=b.z; h[7]=b.w;
    } else {
      u64* src = hbU + (size_t)(par * NREP + grp) * (DD / 2) + 4 * tid;
      const u64 EXP = ((t >> 1) & 1) ? SIGN2 : 0ULL;
      u64 u0, u1, u2, u3;
      for (;;) {
        u0 = aload(src + 0); u1 = aload(src + 1);
        u2 = aload(src + 2); u3 = aload(src + 3);
        if (((((u0 ^ EXP) | (u1 ^ EXP)) | ((u2 ^ EXP) | (u3 ^ EXP))) & SIGN2) == 0ULL)
          break;
        __builtin_amdgcn_s_sleep(1);
      }
      u0 &= ~SIGN2; u1 &= ~SIGN2; u2 &= ~SIGN2; u3 &= ~SIGN2;
      h[0]=__uint_as_float((unsigned)u0); h[1]=__uint_as_float((unsigned)(u0>>32));
      h[2]=__uint_as_float((unsigned)u1); h[3]=__uint_as_float((unsigned)(u1>>32));
      h[4]=__uint_as_float((unsigned)u2); h[5]=__uint_as_float((unsigned)(u2>>32));
      h[6]=__uint_as_float((unsigned)u3); h[7]=__uint_as_float((unsigned)(u3>>32));
    }

    // Straight-from-registers partial GEMV: 16 (permuted) rows x my 8 k.
    float acc[RPW];
#pragma unroll
    for (int r = 0; r < RPW; ++r) acc[r] = 0.f;
#pragma unroll
    for (int i = 0; i < 8; ++i)
#pragma unroll
      for (int r = 0; r < RPW; ++r) acc[r] += w2[r * 8 + i] * h[i];

    // Butterfly fold: 16 rows x 64 lanes in 17 shuffles + 17 adds.
#pragma unroll
    for (int j = 0; j < 8; ++j) acc[j] += __shfl_xor(acc[8 + j], 1, 64);
#pragma unroll
    for (int j = 0; j < 4; ++j) acc[j] += __shfl_xor(acc[4 + j], 2, 64);
#pragma unroll
    for (int j = 0; j < 2; ++j) acc[j] += __shfl_xor(acc[2 + j], 4, 64);
    acc[0] += __shfl_xor(acc[1], 8, 64);
    acc[0] += __shfl_xor(acc[0], 16, 64);
    acc[0] += __shfl_xor(acc[0], 32, 64);

    if (lane < 16) partial[par][wave][lp] = acc[0];
    asm volatile("s_waitcnt lgkmcnt(0)" ::: "memory");   // partial visible
    int old = 0;
    if (lane == 0) old = atomicAdd(&scnt[par], 1);
    old = __shfl(old, 0, 64);

    if (old == 3) {
      // Last-arriving wave combines + stores (all 64 lanes).
      asm volatile("" ::: "memory");
      float v = partial[par][lane >> 4][lane & 15];
      v += __shfl_xor(v, 16, 64);
      v += __shfl_xor(v, 32, 64);          // full row sum, replicated x4
      if (lane == 0) scnt[par] = 0;        // reset for reuse at t+2
      asm volatile("s_waitcnt lgkmcnt(0)" ::: "memory");
      const float r = fmaxf(v + preh + b2v, 0.f);
      u32 bits = __float_as_uint(r);       // sign bit 0 (r >= 0)
      if (((t + 1) >> 1) & 1) bits |= SIGN1;
      const int slot8 = ((t + 1) & 1) * NREP;
      // lanes 0..63: rep = lane>>4 (0..3) and +4; 16 consecutive dwords per
      // 16-lane group = coalesced full-64B-line store from this single wave.
      u32* b0 = (u32*)hbuf + (size_t)(slot8 + (lane >> 4)) * DD + crow;
      astore32(b0, bits);
      astore32(b0 + 4 * DD, bits);
    }
  }

  if (wg != 0) return;

  // WG0 epilogue: out = Wf @ h_TT + bf. h_8192: slot 0, rep 0, tag 0.
  {
    u64* src = hbU + 4 * tid;
    u64 u0, u1, u2, u3;
    for (;;) {
      u0 = aload(src + 0); u1 = aload(src + 1);
      u2 = aload(src + 2); u3 = aload(src + 3);
      if ((((u0 | u1) | (u2 | u3)) & SIGN2) == 0ULL) break;
      __builtin_amdgcn_s_sleep(1);
    }
    u64* dst = (u64*)hs + 4 * tid;
    dst[0] = u0; dst[1] = u1; dst[2] = u2; dst[3] = u3;
  }
  __syncthreads();
  float acc = 0.f;
#pragma unroll
  for (int j = 0; j < 8; ++j) {
    const float4 wv = *(const float4*)(Wf + (size_t)wave * DD + j * 256 + 4 * lane);
    const float4 hv = *(const float4*)&hs[j * 256 + 4 * lane];
    acc += wv.x * hv.x + wv.y * hv.y + wv.z * hv.z + wv.w * hv.w;
  }
  acc = wave_sum(acc);
  if (lane == 0) out[wave] = acc + bf[wave];
}

// ---------------- Launch ----------------------------------------------------
extern "C" void kernel_launch(void* const* d_in, const int* in_sizes, int n_in,
                              void* d_out, int out_size, void* d_ws, size_t ws_size,
                              hipStream_t stream) {
  const float* x  = (const float*)d_in[0];
  const float* h0 = (const float*)d_in[1];
  const float* W1 = (const float*)d_in[2];
  const float* b1 = (const float*)d_in[3];
  const float* W2 = (const float*)d_in[4];
  const float* b2 = (const float*)d_in[5];
  const float* Wf = (const float*)d_in[6];
  const float* bf = (const float*)d_in[7];
  float* out = (float*)d_out;

  // Workspace: pre (64 MB) | hbuf (2 slots x NREP x DD floats = 128 KB)
  float* pre  = (float*)d_ws;
  float* hbuf = pre + (size_t)TT * DD;

  // Anti-poison slot init (see kernel comment).
  hipMemsetAsync(hbuf, 0x00, NREP * DD * sizeof(float), stream);              // slot0
  hipMemsetAsync(hbuf + NREP * DD, 0xAA, NREP * DD * sizeof(float), stream);  // slot1

  gemm_abt_bias<<<dim3((TT / BM) * (DD / BN)), dim3(NTH), 0, stream>>>(
      x, W1, b1, pre, TT, DD, DD);
  recurrent_kernel<<<dim3(NWG), dim3(NTH), 0, stream>>>(
      h0, W2, b2, pre, Wf, bf, out, hbuf);
}